// Round 14
// baseline (10657.759 us; speedup 1.0000x reference)
//
#include <hip/hip_runtime.h>

typedef _Float16 f16;
typedef _Float16 f16x8 __attribute__((ext_vector_type(8)));
typedef float f32x4 __attribute__((ext_vector_type(4)));
typedef unsigned long long u64;

#define BB 64
#define TT 1024
#define TP 1028
#define DD 512

// ---------------- ws layout (bytes) ----------------
static constexpr size_t SZ_XPAD = (size_t)BB * TP * DD * 2;
static constexpr size_t OFF_XA  = 0;
static constexpr size_t OFF_XB  = OFF_XA + SZ_XPAD;
static constexpr size_t OFF_KWA = OFF_XB + SZ_XPAD;
static constexpr size_t SZ_KWA  = (size_t)480 * 16384;
static constexpr size_t OFF_WKA = OFF_KWA + SZ_KWA;
static constexpr size_t SZ_WKA  = (size_t)128 * 16384;
static constexpr size_t OFF_WRA = OFF_WKA + SZ_WKA;
static constexpr size_t SZ_WRA  = (size_t)524288 * 2;
static constexpr size_t OFF_SCSH= OFF_WRA + SZ_WRA;
static constexpr size_t OFF_PRE = OFF_SCSH + 4096;
static constexpr size_t SZ_PRE  = (size_t)BB * TT * 2048 * 2;
static constexpr size_t OFF_HG  = OFF_PRE + SZ_PRE;   // [16 wg][2 parity][16 row][128 u] f16 = 128KB
static constexpr size_t SZ_HG   = (size_t)16 * 8192;

// ---------------- helpers ----------------
__device__ __forceinline__ void gld16(const void* g, void* l) {
  __builtin_amdgcn_global_load_lds(
      (const __attribute__((address_space(1))) unsigned*)g,
      (__attribute__((address_space(3))) unsigned*)l, 16, 0, 0);
}

// rcp-based gates (R11-proven, absmax unchanged)
__device__ __forceinline__ float sigm(float x) {
  return __builtin_amdgcn_rcpf(1.f + __expf(-x));
}
__device__ __forceinline__ float tanh_(float x) {
  float e = __expf(2.f * fminf(x, 15.f));
  return (e - 1.f) * __builtin_amdgcn_rcpf(e + 1.f);
}

// ---------------- prep kernels ----------------
// Fill hg with tag-safe patterns EVERY launch (poison/replay safe):
// parity 0 buffers <- f16 bits 0x0001 (tag 1; parity-0 steps expect tags {0,2})
// parity 1 buffers <- f16 bits 0x0000 (tag 0; parity-1 steps expect tags {1,3})
__global__ void prep_scale(const float* __restrict__ cb, const float* __restrict__ gm,
                           const float* __restrict__ bt, const float* __restrict__ mn,
                           const float* __restrict__ vr, float* __restrict__ scsh,
                           unsigned* __restrict__ hgw) {
  int i = blockIdx.x * 256 + threadIdx.x;   // grid 128*256 = 32768 words = 128KB
  hgw[i] = ((i >> 10) & 1) ? 0u : 0x00010001u;
  if (i < 3 * 512) {
    float rs = rsqrtf(vr[i] + 1e-3f);
    float s = gm[i] * rs;
    scsh[i] = s;
    scsh[1536 + i] = (cb[i] - mn[i]) * s + bt[i];
  }
}

__global__ void prep_x(const float* __restrict__ x, f16* __restrict__ xa, f16* __restrict__ xb) {
  size_t idx = (size_t)blockIdx.x * 256 + threadIdx.x;
  int d = (int)(idx & 511);
  int r = (int)(idx >> 9);
  int t2 = r % TP;
  int b = r / TP;
  int t = t2 - 2;
  bool in = (t >= 0 && t < TT);
  f16 v = in ? (f16)x[((size_t)b * TT + t) * DD + d] : (f16)0.f;
  xa[idx] = v;
  if (!in) xb[idx] = (f16)0.f;
}

__global__ void prep_convw(const float* __restrict__ ck, f16* __restrict__ kwa) {
  size_t idx = (size_t)blockIdx.x * 256 + threadIdx.x;
  int dout = (int)(idx & 511);
  int din = (int)((idx >> 9) & 511);
  int k5 = (int)((idx >> 18) % 5);
  int l = (int)(idx / ((size_t)5 << 18));
  f16 v = (f16)ck[idx];
  int blk = ((l * 5 + k5) * 4 + (dout >> 7)) * 8 + (din >> 6);
  int n = dout & 127, kk = din & 63;
  size_t dst = (size_t)blk * 8192 + (size_t)n * 64 + (size_t)(((kk >> 3) ^ (n & 7)) * 8) + (kk & 7);
  kwa[dst] = v;
}

__global__ void prep_wk(const float* __restrict__ wf, const float* __restrict__ wb2, f16* __restrict__ wka) {
  size_t idx = (size_t)blockIdx.x * 256 + threadIdx.x;
  int c = (int)(idx & 2047);
  int din = (int)(idx >> 11);
  float s = (c < 1024) ? wf[(size_t)din * 1024 + c] : wb2[(size_t)din * 1024 + (c - 1024)];
  int blk = (c >> 7) * 8 + (din >> 6);
  int n = c & 127, kk = din & 63;
  size_t dst = (size_t)blk * 8192 + (size_t)n * 64 + (size_t)(((kk >> 3) ^ (n & 7)) * 8) + (kk & 7);
  wka[dst] = (f16)s;
}

__global__ void prep_wr(const float* __restrict__ wf, const float* __restrict__ wb2, f16* __restrict__ wra) {
  size_t idx = (size_t)blockIdx.x * 256 + threadIdx.x;   // 2*256*1024
  int c = (int)(idx & 1023);
  int k = (int)((idx >> 10) & 255);
  int dir = (int)(idx >> 18);
  float s = dir ? wb2[(size_t)k * 1024 + c] : wf[(size_t)k * 1024 + c];
  int gate = c >> 8;
  int u = c & 255;
  int ssub = u >> 4;
  int hf = ssub >> 3, w = ssub & 7;
  int l15 = u & 15;
  int ks = k >> 5, lhi = (k >> 3) & 3, j = k & 7;
  int lane = lhi * 16 + l15;
  size_t dst = ((((size_t)(dir * 2 + hf) * 8 + w) * 4 + gate) * 8 + ks) * 512 + (size_t)lane * 8 + j;
  wra[dst] = (f16)s;
}

// ---------------- conv layer ----------------
__global__ __launch_bounds__(256, 3) void conv_gemm(
    const f16* __restrict__ xin, f16* __restrict__ xout,
    const f16* __restrict__ kwb, const float* __restrict__ scl, const float* __restrict__ shl) {
  __shared__ f16 Al[8192];
  __shared__ f16 Bl[8192];
  const int tid = threadIdx.x;
  const int lane = tid & 63;
  const int w = tid >> 6, wm = w >> 1, wn = w & 1;
  const int r15 = lane & 15, lhi = lane >> 4;
  const int wg = blockIdx.x;
  const int tm = wg >> 2, nb = wg & 3;
  const int b = tm >> 3, tblk = tm & 7;
  const size_t abase = (size_t)b * TP + (size_t)tblk * 128;

  int srow[4], asoff[4];
#pragma unroll
  for (int p = 0; p < 4; ++p) {
    int L = tid * 16 + p * 4096;
    int row = L >> 7, ch = (L >> 4) & 7;
    srow[p] = row;
    asoff[p] = (ch ^ (row & 7)) * 8;
  }

  f32x4 acc[4][4] = {};

  for (int k5 = 0; k5 < 5; ++k5) {
    for (int kb = 0; kb < 8; ++kb) {
#pragma unroll
      for (int p = 0; p < 4; ++p) {
        const f16* asrc = xin + (abase + (size_t)(k5 + srow[p])) * DD + kb * 64 + asoff[p];
        gld16(asrc, (char*)Al + tid * 16 + p * 4096);
      }
      const char* bbase = (const char*)kwb + (size_t)((k5 * 4 + nb) * 8 + kb) * 16384;
#pragma unroll
      for (int p = 0; p < 4; ++p)
        gld16(bbase + tid * 16 + p * 4096, (char*)Bl + tid * 16 + p * 4096);
      __syncthreads();
#pragma unroll
      for (int ks = 0; ks < 2; ++ks) {
        f16x8 af[4], bf[4];
#pragma unroll
        for (int m = 0; m < 4; ++m) {
          int row = wm * 64 + m * 16 + r15;
          int rc = (ks * 4 + lhi) ^ (row & 7);
          af[m] = *(const f16x8*)((const char*)Al + row * 128 + rc * 16);
        }
#pragma unroll
        for (int n = 0; n < 4; ++n) {
          int row = wn * 64 + n * 16 + r15;
          int rc = (ks * 4 + lhi) ^ (row & 7);
          bf[n] = *(const f16x8*)((const char*)Bl + row * 128 + rc * 16);
        }
#pragma unroll
        for (int m = 0; m < 4; ++m)
#pragma unroll
          for (int n = 0; n < 4; ++n)
            acc[m][n] = __builtin_amdgcn_mfma_f32_16x16x32_f16(af[m], bf[n], acc[m][n], 0, 0, 0);
      }
      __syncthreads();
    }
  }
#pragma unroll
  for (int n = 0; n < 4; ++n) {
    int c = nb * 128 + wn * 64 + n * 16 + r15;
    float s_ = scl[c], h_ = shl[c];
#pragma unroll
    for (int m = 0; m < 4; ++m) {
      int rl = wm * 64 + m * 16 + lhi * 4;
#pragma unroll
      for (int j = 0; j < 4; ++j) {
        float v = fmaxf(acc[m][n][j] * s_ + h_, 0.f);
        unsigned short us = __builtin_bit_cast(unsigned short, (f16)v);
        unsigned ot = (unsigned)__shfl_xor((int)us, 1, 64);
        if (!(lane & 1)) {
          unsigned pk = (unsigned)us | (ot << 16);
          *(unsigned*)((char*)xout + ((abase + 2 + rl + j) * DD + c) * 2) = pk;
        }
      }
    }
  }
}

// ---------------- LSTM input GEMM ----------------
__global__ __launch_bounds__(256, 3) void in_gemm(
    const f16* __restrict__ xin, f16* __restrict__ pre, const f16* __restrict__ wkb,
    const float* __restrict__ bfw, const float* __restrict__ bbw) {
  __shared__ f16 Al[8192];
  __shared__ f16 Bl[8192];
  const int tid = threadIdx.x;
  const int lane = tid & 63;
  const int w = tid >> 6, wm = w >> 1, wn = w & 1;
  const int r15 = lane & 15, lhi = lane >> 4;
  const int wg = blockIdx.x;
  const int tm = wg >> 4, nb = wg & 15;
  const int b = tm >> 3, tblk = tm & 7;
  const size_t abase = (size_t)b * TP + (size_t)tblk * 128 + 2;

  int srow[4], asoff[4];
#pragma unroll
  for (int p = 0; p < 4; ++p) {
    int L = tid * 16 + p * 4096;
    int row = L >> 7, ch = (L >> 4) & 7;
    srow[p] = row;
    asoff[p] = (ch ^ (row & 7)) * 8;
  }

  f32x4 acc[4][4] = {};

  for (int kb = 0; kb < 8; ++kb) {
#pragma unroll
    for (int p = 0; p < 4; ++p) {
      const f16* asrc = xin + (abase + (size_t)srow[p]) * DD + kb * 64 + asoff[p];
      gld16(asrc, (char*)Al + tid * 16 + p * 4096);
    }
    const char* bbase = (const char*)wkb + (size_t)(nb * 8 + kb) * 16384;
#pragma unroll
    for (int p = 0; p < 4; ++p)
      gld16(bbase + tid * 16 + p * 4096, (char*)Bl + tid * 16 + p * 4096);
    __syncthreads();
#pragma unroll
    for (int ks = 0; ks < 2; ++ks) {
      f16x8 af[4], bf[4];
#pragma unroll
      for (int m = 0; m < 4; ++m) {
        int row = wm * 64 + m * 16 + r15;
        int rc = (ks * 4 + lhi) ^ (row & 7);
        af[m] = *(const f16x8*)((const char*)Al + row * 128 + rc * 16);
      }
#pragma unroll
      for (int n = 0; n < 4; ++n) {
        int row = wn * 64 + n * 16 + r15;
        int rc = (ks * 4 + lhi) ^ (row & 7);
        bf[n] = *(const f16x8*)((const char*)Bl + row * 128 + rc * 16);
      }
#pragma unroll
      for (int m = 0; m < 4; ++m)
#pragma unroll
        for (int n = 0; n < 4; ++n)
          acc[m][n] = __builtin_amdgcn_mfma_f32_16x16x32_f16(af[m], bf[n], acc[m][n], 0, 0, 0);
    }
    __syncthreads();
  }
#pragma unroll
  for (int n = 0; n < 4; ++n) {
    int c = nb * 128 + wn * 64 + n * 16 + r15;
    float bias = (c < 1024) ? bfw[c] : bbw[c - 1024];
#pragma unroll
    for (int m = 0; m < 4; ++m) {
      int rl = wm * 64 + m * 16 + lhi * 4;
#pragma unroll
      for (int j = 0; j < 4; ++j) {
        float v = acc[m][n][j] + bias;
        unsigned short us = __builtin_bit_cast(unsigned short, (f16)v);
        unsigned ot = (unsigned)__shfl_xor((int)us, 1, 64);
        if (!(lane & 1)) {
          unsigned pk = (unsigned)us | (ot << 16);
          size_t prow = (size_t)b * TT + tblk * 128 + rl + j;
          *(unsigned*)((char*)pre + (prow * 2048 + c) * 2) = pk;
        }
      }
    }
  }
}

// ---------------- recurrence: tagged-f16 exchange, own-half MFMA in the V-window ----------------
// 16 wgs (dir = wg>>3, bblk = (wg>>1)&3, half = wg&1), partner = wg^1.
// Step s: B1 (own-h visible) -> pld + OWN-half MFMA (overlaps partner publish propagation)
//   -> double-pumped tagged poll -> stage -> B2 -> PARTNER-half MFMA -> gates -> publish.
__global__ __launch_bounds__(512, 2) void lstm_rec(
    const f16* __restrict__ wra, const f16* __restrict__ pre, float* __restrict__ out,
    unsigned* __restrict__ hg) {
  __shared__ f16 hl[2][16 * 264];   // [parity][16 rows][256 u + 8 pad] (528B row stride)
  const int wg = blockIdx.x;
  const int dir = wg >> 3, bblk = (wg >> 1) & 3, half = wg & 1;
  const int ph = half ^ 1;
  const int pwg = wg ^ 1;
  const int tid = threadIdx.x;
  const int lane = tid & 63, w = tid >> 6;
  const int r15 = lane & 15, lhi = lane >> 4;
  const int ulocal = w * 16 + r15;
  const int u = half * 128 + ulocal;          // global u of this lane's column
  const int b0 = bblk * 16 + lhi * 4;         // global batch base of this lane's 4 rows

  // B fragments: 4 gates x 8 k-tiles (128 regs; AGPR-resident ok on gfx950)
  f16x8 bfr[4][8];
  {
    const f16* wb0 = wra + (((size_t)(dir * 2 + half) * 8 + w) * 4) * 8 * 512;
#pragma unroll
    for (int g = 0; g < 4; ++g)
#pragma unroll
      for (int ks = 0; ks < 8; ++ks)
        bfr[g][ks] = *(const f16x8*)(wb0 + ((size_t)g * 8 + ks) * 512 + (size_t)lane * 8);
  }

  for (int i = tid; i < 2 * 16 * 264; i += 512) ((f16*)hl)[i] = (f16)0.f;
  float cst[4] = {0.f, 0.f, 0.f, 0.f};
  const u64* pstage = (const u64*)((const char*)hg + (size_t)pwg * 8192);  // [2 par][512 u64]
  unsigned* myhg = (unsigned*)((char*)hg + (size_t)wg * 8192);             // [2 par][1024 u32]
  const int srow = tid >> 5;          // stage row (32 u64 per row)
  const int schunk = tid & 31;        // stage 8B chunk within 128-f16 half

  // pointer-increment addressing for pre/out (g offsets are 13-bit immediates)
  const unsigned short* pr16 = (const unsigned short*)pre;
  const int t0 = dir ? (TT - 1) : 0;
  const ptrdiff_t sPre = dir ? -2048 : 2048;            // u16 elems per t-step
  const ptrdiff_t sOut = dir ? -(ptrdiff_t)DD : DD;     // f32 elems per t-step
  const unsigned short* prp[4];
  float* outp[4];
#pragma unroll
  for (int j = 0; j < 4; ++j) {
    prp[j]  = pr16 + ((size_t)(b0 + j) * TT + t0) * 2048 + dir * 1024 + u;
    outp[j] = out  + ((size_t)(b0 + j) * TT + t0) * DD   + dir * 256  + u;
  }

  for (int s = 0; s < TT; ++s) {
    __syncthreads();   // B1: own-h(s-1) writes to hl[s&1] visible to all waves

    // pre loads (latency hides under own-MFMA + poll)
    unsigned short pld[4][4];
#pragma unroll
    for (int g = 0; g < 4; ++g)
#pragma unroll
      for (int j = 0; j < 4; ++j)
        pld[g][j] = prp[j][g * 256];

    // OWN-half MFMA (4 k-tiles) — runs inside the partner-visibility window
    f32x4 accv[4] = {};
    const char* hb = (const char*)hl[s & 1];
#pragma unroll
    for (int q = 0; q < 4; ++q) {
      f16x8 af = *(const f16x8*)(hb + r15 * 528 + (half * 4 + q) * 64 + lhi * 16);
#pragma unroll
      for (int g = 0; g < 4; ++g)
        accv[g] = __builtin_amdgcn_mfma_f32_16x16x32_f16(af, bfr[g][half * 4 + q], accv[g], 0, 0, 0);
    }

    if (s > 0) {
      // double-pumped tagged poll: data load IS the readiness signal
      const u64* pb = pstage + (size_t)(s & 1) * 512 + tid;
      const u64 expv = 0x0001000100010001ULL * (u64)(s & 3);
      u64 v8;
      for (;;) {
        u64 a = __hip_atomic_load(pb, __ATOMIC_RELAXED, __HIP_MEMORY_SCOPE_AGENT);
        u64 b2 = __hip_atomic_load(pb, __ATOMIC_RELAXED, __HIP_MEMORY_SCOPE_AGENT);
        if (((a ^ expv) & 0x0003000300030003ULL) == 0) { v8 = a; break; }
        if (((b2 ^ expv) & 0x0003000300030003ULL) == 0) { v8 = b2; break; }
      }
      *(u64*)((char*)hl[s & 1] + srow * 528 + ph * 256 + schunk * 8) = v8;
    }
    __syncthreads();   // B2: partner half staged

    // PARTNER-half MFMA (4 k-tiles)
#pragma unroll
    for (int q = 0; q < 4; ++q) {
      f16x8 af = *(const f16x8*)(hb + r15 * 528 + (ph * 4 + q) * 64 + lhi * 16);
#pragma unroll
      for (int g = 0; g < 4; ++g)
        accv[g] = __builtin_amdgcn_mfma_f32_16x16x32_f16(af, bfr[g][ph * 4 + q], accv[g], 0, 0, 0);
    }

    // gates (rcp transcendentals)
    float hv[4];
#pragma unroll
    for (int j = 0; j < 4; ++j) {
      float zi = accv[0][j] + (float)__builtin_bit_cast(f16, pld[0][j]);
      float zf = accv[1][j] + (float)__builtin_bit_cast(f16, pld[1][j]);
      float zg = accv[2][j] + (float)__builtin_bit_cast(f16, pld[2][j]);
      float zo = accv[3][j] + (float)__builtin_bit_cast(f16, pld[3][j]);
      float ig = sigm(zi), fg = sigm(zf), gg = tanh_(zg), og = sigm(zo);
      float cc = fg * cst[j] + ig * gg;
      cst[j] = cc;
      hv[j] = og * tanh_(cc);
    }

    // publish IMMEDIATELY: tagged packed pairs, fire-and-forget
    const unsigned tg2 = (unsigned)((s + 1) & 3);
    unsigned short t0_ = (unsigned short)((__builtin_bit_cast(unsigned short, (f16)hv[0]) & 0xFFFCu) | tg2);
    unsigned short t1_ = (unsigned short)((__builtin_bit_cast(unsigned short, (f16)hv[1]) & 0xFFFCu) | tg2);
    unsigned short t2_ = (unsigned short)((__builtin_bit_cast(unsigned short, (f16)hv[2]) & 0xFFFCu) | tg2);
    unsigned short t3_ = (unsigned short)((__builtin_bit_cast(unsigned short, (f16)hv[3]) & 0xFFFCu) | tg2);
    {
      unsigned o0 = (unsigned)__shfl_xor((int)t0_, 1, 64);
      unsigned o1 = (unsigned)__shfl_xor((int)t1_, 1, 64);
      unsigned o2 = (unsigned)__shfl_xor((int)t2_, 1, 64);
      unsigned o3 = (unsigned)__shfl_xor((int)t3_, 1, 64);
      if (!(lane & 1)) {
        unsigned* so = myhg + (size_t)((s + 1) & 1) * 1024 + (lhi * 4) * 64 + (ulocal >> 1);
        __hip_atomic_store(so,       (unsigned)t0_ | (o0 << 16), __ATOMIC_RELAXED, __HIP_MEMORY_SCOPE_AGENT);
        __hip_atomic_store(so + 64,  (unsigned)t1_ | (o1 << 16), __ATOMIC_RELAXED, __HIP_MEMORY_SCOPE_AGENT);
        __hip_atomic_store(so + 128, (unsigned)t2_ | (o2 << 16), __ATOMIC_RELAXED, __HIP_MEMORY_SCOPE_AGENT);
        __hip_atomic_store(so + 192, (unsigned)t3_ | (o3 << 16), __ATOMIC_RELAXED, __HIP_MEMORY_SCOPE_AGENT);
      }
    }

    // own h into next-parity LDS (read after next step's B1), then out stores
    {
      f16* hn = hl[(s + 1) & 1];
#pragma unroll
      for (int j = 0; j < 4; ++j)
        hn[(lhi * 4 + j) * 264 + half * 128 + ulocal] = (f16)hv[j];
    }
#pragma unroll
    for (int j = 0; j < 4; ++j) {
      *outp[j] = hv[j];
      outp[j] += sOut;
      prp[j]  += sPre;
    }
  }
}

// ---------------- launch ----------------
extern "C" void kernel_launch(void* const* d_in, const int* in_sizes, int n_in,
                              void* d_out, int out_size, void* d_ws, size_t ws_size,
                              hipStream_t stream) {
  (void)in_sizes; (void)n_in; (void)out_size; (void)ws_size;
  char* ws = (char*)d_ws;
  f16* xa   = (f16*)(ws + OFF_XA);
  f16* xb   = (f16*)(ws + OFF_XB);
  f16* kwa  = (f16*)(ws + OFF_KWA);
  f16* wka  = (f16*)(ws + OFF_WKA);
  f16* wra  = (f16*)(ws + OFF_WRA);
  float* scsh = (float*)(ws + OFF_SCSH);
  f16* pre  = (f16*)(ws + OFF_PRE);
  unsigned* hg = (unsigned*)(ws + OFF_HG);

  const float* x   = (const float*)d_in[0];
  const float* ck  = (const float*)d_in[1];
  const float* cb  = (const float*)d_in[2];
  const float* gm  = (const float*)d_in[3];
  const float* bt  = (const float*)d_in[4];
  const float* mn  = (const float*)d_in[5];
  const float* vr  = (const float*)d_in[6];
  const float* wkf = (const float*)d_in[7];
  const float* wrf = (const float*)d_in[8];
  const float* bf  = (const float*)d_in[9];
  const float* wkb = (const float*)d_in[10];
  const float* wrb = (const float*)d_in[11];
  const float* bb2 = (const float*)d_in[12];

  prep_scale<<<128, 256, 0, stream>>>(cb, gm, bt, mn, vr, scsh, hg);
  prep_x<<<(BB * TP * DD) / 256, 256, 0, stream>>>(x, xa, xb);
  prep_convw<<<(3 * 5 * 512 * 512) / 256, 256, 0, stream>>>(ck, kwa);
  prep_wk<<<(512 * 2048) / 256, 256, 0, stream>>>(wkf, wkb, wka);
  prep_wr<<<(2 * 256 * 1024) / 256, 256, 0, stream>>>(wrf, wrb, wra);

  conv_gemm<<<2048, 256, 0, stream>>>(xa, xb, kwa,                  scsh,          scsh + 1536);
  conv_gemm<<<2048, 256, 0, stream>>>(xb, xa, kwa + 1 * 160 * 8192, scsh + 512,   scsh + 1536 + 512);
  conv_gemm<<<2048, 256, 0, stream>>>(xa, xb, kwa + 2 * 160 * 8192, scsh + 1024,  scsh + 1536 + 1024);

  in_gemm<<<8192, 256, 0, stream>>>(xb, pre, wka, bf, bb2);

  lstm_rec<<<16, 512, 0, stream>>>(wra, pre, (float*)d_out, hg);
}

// Round 15
// 3560.736 us; speedup vs baseline: 2.9931x; 2.9931x over previous
//
#include <hip/hip_runtime.h>

typedef _Float16 f16;
typedef _Float16 f16x8 __attribute__((ext_vector_type(8)));
typedef float f32x4 __attribute__((ext_vector_type(4)));
typedef unsigned long long u64;

#define BB 64
#define TT 1024
#define TP 1028
#define DD 512

// ---------------- ws layout (bytes) ----------------
static constexpr size_t SZ_XPAD = (size_t)BB * TP * DD * 2;
static constexpr size_t OFF_XA  = 0;
static constexpr size_t OFF_XB  = OFF_XA + SZ_XPAD;
static constexpr size_t OFF_KWA = OFF_XB + SZ_XPAD;
static constexpr size_t SZ_KWA  = (size_t)480 * 16384;
static constexpr size_t OFF_WKA = OFF_KWA + SZ_KWA;
static constexpr size_t SZ_WKA  = (size_t)128 * 16384;
static constexpr size_t OFF_WRA = OFF_WKA + SZ_WKA;
static constexpr size_t SZ_WRA  = (size_t)524288 * 2;
static constexpr size_t OFF_SCSH= OFF_WRA + SZ_WRA;
static constexpr size_t OFF_PRE = OFF_SCSH + 4096;
static constexpr size_t SZ_PRE  = (size_t)BB * TT * 2048 * 2;
static constexpr size_t OFF_HG  = OFF_PRE + SZ_PRE;   // [16 wg][2 parity][16 row][128 u] f16 = 128KB
static constexpr size_t SZ_HG   = (size_t)16 * 8192;

// ---------------- helpers ----------------
__device__ __forceinline__ void gld16(const void* g, void* l) {
  __builtin_amdgcn_global_load_lds(
      (const __attribute__((address_space(1))) unsigned*)g,
      (__attribute__((address_space(3))) unsigned*)l, 16, 0, 0);
}

// rcp-based gates (R11-proven, absmax unchanged)
__device__ __forceinline__ float sigm(float x) {
  return __builtin_amdgcn_rcpf(1.f + __expf(-x));
}
__device__ __forceinline__ float tanh_(float x) {
  float e = __expf(2.f * fminf(x, 15.f));
  return (e - 1.f) * __builtin_amdgcn_rcpf(e + 1.f);
}

// ---------------- prep kernels ----------------
// Fill hg with tag-safe patterns EVERY launch (poison/replay safe):
// parity 0 buffers <- f16 bits 0x0001 (tag 1; parity-0 steps expect tags {0,2})
// parity 1 buffers <- f16 bits 0x0000 (tag 0; parity-1 steps expect tags {1,3})
__global__ void prep_scale(const float* __restrict__ cb, const float* __restrict__ gm,
                           const float* __restrict__ bt, const float* __restrict__ mn,
                           const float* __restrict__ vr, float* __restrict__ scsh,
                           unsigned* __restrict__ hgw) {
  int i = blockIdx.x * 256 + threadIdx.x;   // grid 128*256 = 32768 words = 128KB
  hgw[i] = ((i >> 10) & 1) ? 0u : 0x00010001u;
  if (i < 3 * 512) {
    float rs = rsqrtf(vr[i] + 1e-3f);
    float s = gm[i] * rs;
    scsh[i] = s;
    scsh[1536 + i] = (cb[i] - mn[i]) * s + bt[i];
  }
}

__global__ void prep_x(const float* __restrict__ x, f16* __restrict__ xa, f16* __restrict__ xb) {
  size_t idx = (size_t)blockIdx.x * 256 + threadIdx.x;
  int d = (int)(idx & 511);
  int r = (int)(idx >> 9);
  int t2 = r % TP;
  int b = r / TP;
  int t = t2 - 2;
  bool in = (t >= 0 && t < TT);
  f16 v = in ? (f16)x[((size_t)b * TT + t) * DD + d] : (f16)0.f;
  xa[idx] = v;
  if (!in) xb[idx] = (f16)0.f;
}

__global__ void prep_convw(const float* __restrict__ ck, f16* __restrict__ kwa) {
  size_t idx = (size_t)blockIdx.x * 256 + threadIdx.x;
  int dout = (int)(idx & 511);
  int din = (int)((idx >> 9) & 511);
  int k5 = (int)((idx >> 18) % 5);
  int l = (int)(idx / ((size_t)5 << 18));
  f16 v = (f16)ck[idx];
  int blk = ((l * 5 + k5) * 4 + (dout >> 7)) * 8 + (din >> 6);
  int n = dout & 127, kk = din & 63;
  size_t dst = (size_t)blk * 8192 + (size_t)n * 64 + (size_t)(((kk >> 3) ^ (n & 7)) * 8) + (kk & 7);
  kwa[dst] = v;
}

__global__ void prep_wk(const float* __restrict__ wf, const float* __restrict__ wb2, f16* __restrict__ wka) {
  size_t idx = (size_t)blockIdx.x * 256 + threadIdx.x;
  int c = (int)(idx & 2047);
  int din = (int)(idx >> 11);
  float s = (c < 1024) ? wf[(size_t)din * 1024 + c] : wb2[(size_t)din * 1024 + (c - 1024)];
  int blk = (c >> 7) * 8 + (din >> 6);
  int n = c & 127, kk = din & 63;
  size_t dst = (size_t)blk * 8192 + (size_t)n * 64 + (size_t)(((kk >> 3) ^ (n & 7)) * 8) + (kk & 7);
  wka[dst] = (f16)s;
}

__global__ void prep_wr(const float* __restrict__ wf, const float* __restrict__ wb2, f16* __restrict__ wra) {
  size_t idx = (size_t)blockIdx.x * 256 + threadIdx.x;   // 2*256*1024
  int c = (int)(idx & 1023);
  int k = (int)((idx >> 10) & 255);
  int dir = (int)(idx >> 18);
  float s = dir ? wb2[(size_t)k * 1024 + c] : wf[(size_t)k * 1024 + c];
  int gate = c >> 8;
  int u = c & 255;
  int ssub = u >> 4;
  int hf = ssub >> 3, w = ssub & 7;
  int l15 = u & 15;
  int ks = k >> 5, lhi = (k >> 3) & 3, j = k & 7;
  int lane = lhi * 16 + l15;
  size_t dst = ((((size_t)(dir * 2 + hf) * 8 + w) * 4 + gate) * 8 + ks) * 512 + (size_t)lane * 8 + j;
  wra[dst] = (f16)s;
}

// ---------------- conv layer ----------------
__global__ __launch_bounds__(256, 3) void conv_gemm(
    const f16* __restrict__ xin, f16* __restrict__ xout,
    const f16* __restrict__ kwb, const float* __restrict__ scl, const float* __restrict__ shl) {
  __shared__ f16 Al[8192];
  __shared__ f16 Bl[8192];
  const int tid = threadIdx.x;
  const int lane = tid & 63;
  const int w = tid >> 6, wm = w >> 1, wn = w & 1;
  const int r15 = lane & 15, lhi = lane >> 4;
  const int wg = blockIdx.x;
  const int tm = wg >> 2, nb = wg & 3;
  const int b = tm >> 3, tblk = tm & 7;
  const size_t abase = (size_t)b * TP + (size_t)tblk * 128;

  int srow[4], asoff[4];
#pragma unroll
  for (int p = 0; p < 4; ++p) {
    int L = tid * 16 + p * 4096;
    int row = L >> 7, ch = (L >> 4) & 7;
    srow[p] = row;
    asoff[p] = (ch ^ (row & 7)) * 8;
  }

  f32x4 acc[4][4] = {};

  for (int k5 = 0; k5 < 5; ++k5) {
    for (int kb = 0; kb < 8; ++kb) {
#pragma unroll
      for (int p = 0; p < 4; ++p) {
        const f16* asrc = xin + (abase + (size_t)(k5 + srow[p])) * DD + kb * 64 + asoff[p];
        gld16(asrc, (char*)Al + tid * 16 + p * 4096);
      }
      const char* bbase = (const char*)kwb + (size_t)((k5 * 4 + nb) * 8 + kb) * 16384;
#pragma unroll
      for (int p = 0; p < 4; ++p)
        gld16(bbase + tid * 16 + p * 4096, (char*)Bl + tid * 16 + p * 4096);
      __syncthreads();
#pragma unroll
      for (int ks = 0; ks < 2; ++ks) {
        f16x8 af[4], bf[4];
#pragma unroll
        for (int m = 0; m < 4; ++m) {
          int row = wm * 64 + m * 16 + r15;
          int rc = (ks * 4 + lhi) ^ (row & 7);
          af[m] = *(const f16x8*)((const char*)Al + row * 128 + rc * 16);
        }
#pragma unroll
        for (int n = 0; n < 4; ++n) {
          int row = wn * 64 + n * 16 + r15;
          int rc = (ks * 4 + lhi) ^ (row & 7);
          bf[n] = *(const f16x8*)((const char*)Bl + row * 128 + rc * 16);
        }
#pragma unroll
        for (int m = 0; m < 4; ++m)
#pragma unroll
          for (int n = 0; n < 4; ++n)
            acc[m][n] = __builtin_amdgcn_mfma_f32_16x16x32_f16(af[m], bf[n], acc[m][n], 0, 0, 0);
      }
      __syncthreads();
    }
  }
#pragma unroll
  for (int n = 0; n < 4; ++n) {
    int c = nb * 128 + wn * 64 + n * 16 + r15;
    float s_ = scl[c], h_ = shl[c];
#pragma unroll
    for (int m = 0; m < 4; ++m) {
      int rl = wm * 64 + m * 16 + lhi * 4;
#pragma unroll
      for (int j = 0; j < 4; ++j) {
        float v = fmaxf(acc[m][n][j] * s_ + h_, 0.f);
        unsigned short us = __builtin_bit_cast(unsigned short, (f16)v);
        unsigned ot = (unsigned)__shfl_xor((int)us, 1, 64);
        if (!(lane & 1)) {
          unsigned pk = (unsigned)us | (ot << 16);
          *(unsigned*)((char*)xout + ((abase + 2 + rl + j) * DD + c) * 2) = pk;
        }
      }
    }
  }
}

// ---------------- LSTM input GEMM ----------------
__global__ __launch_bounds__(256, 3) void in_gemm(
    const f16* __restrict__ xin, f16* __restrict__ pre, const f16* __restrict__ wkb,
    const float* __restrict__ bfw, const float* __restrict__ bbw) {
  __shared__ f16 Al[8192];
  __shared__ f16 Bl[8192];
  const int tid = threadIdx.x;
  const int lane = tid & 63;
  const int w = tid >> 6, wm = w >> 1, wn = w & 1;
  const int r15 = lane & 15, lhi = lane >> 4;
  const int wg = blockIdx.x;
  const int tm = wg >> 4, nb = wg & 15;
  const int b = tm >> 3, tblk = tm & 7;
  const size_t abase = (size_t)b * TP + (size_t)tblk * 128 + 2;

  int srow[4], asoff[4];
#pragma unroll
  for (int p = 0; p < 4; ++p) {
    int L = tid * 16 + p * 4096;
    int row = L >> 7, ch = (L >> 4) & 7;
    srow[p] = row;
    asoff[p] = (ch ^ (row & 7)) * 8;
  }

  f32x4 acc[4][4] = {};

  for (int kb = 0; kb < 8; ++kb) {
#pragma unroll
    for (int p = 0; p < 4; ++p) {
      const f16* asrc = xin + (abase + (size_t)srow[p]) * DD + kb * 64 + asoff[p];
      gld16(asrc, (char*)Al + tid * 16 + p * 4096);
    }
    const char* bbase = (const char*)wkb + (size_t)(nb * 8 + kb) * 16384;
#pragma unroll
    for (int p = 0; p < 4; ++p)
      gld16(bbase + tid * 16 + p * 4096, (char*)Bl + tid * 16 + p * 4096);
    __syncthreads();
#pragma unroll
    for (int ks = 0; ks < 2; ++ks) {
      f16x8 af[4], bf[4];
#pragma unroll
      for (int m = 0; m < 4; ++m) {
        int row = wm * 64 + m * 16 + r15;
        int rc = (ks * 4 + lhi) ^ (row & 7);
        af[m] = *(const f16x8*)((const char*)Al + row * 128 + rc * 16);
      }
#pragma unroll
      for (int n = 0; n < 4; ++n) {
        int row = wn * 64 + n * 16 + r15;
        int rc = (ks * 4 + lhi) ^ (row & 7);
        bf[n] = *(const f16x8*)((const char*)Bl + row * 128 + rc * 16);
      }
#pragma unroll
      for (int m = 0; m < 4; ++m)
#pragma unroll
        for (int n = 0; n < 4; ++n)
          acc[m][n] = __builtin_amdgcn_mfma_f32_16x16x32_f16(af[m], bf[n], acc[m][n], 0, 0, 0);
    }
    __syncthreads();
  }
#pragma unroll
  for (int n = 0; n < 4; ++n) {
    int c = nb * 128 + wn * 64 + n * 16 + r15;
    float bias = (c < 1024) ? bfw[c] : bbw[c - 1024];
#pragma unroll
    for (int m = 0; m < 4; ++m) {
      int rl = wm * 64 + m * 16 + lhi * 4;
#pragma unroll
      for (int j = 0; j < 4; ++j) {
        float v = acc[m][n][j] + bias;
        unsigned short us = __builtin_bit_cast(unsigned short, (f16)v);
        unsigned ot = (unsigned)__shfl_xor((int)us, 1, 64);
        if (!(lane & 1)) {
          unsigned pk = (unsigned)us | (ot << 16);
          size_t prow = (size_t)b * TT + tblk * 128 + rl + j;
          *(unsigned*)((char*)pre + (prow * 2048 + c) * 2) = pk;
        }
      }
    }
  }
}

// ---------------- recurrence: R9 tagged-f16 exchange + rcp gates + ptr-increment epilogue ----------------
// 16 wgs (dir = wg>>3, bblk = (wg>>1)&3, half = wg&1), partner = wg^1.
// Producer step s: h(s) -> hg parity (s+1)&1, each f16 low-2-bits = (s+1)&3.  Fire-and-forget.
// Consumer step s: retry own u64 of partner parity s&1 until all 4 tags == s&3, stage to LDS.
__global__ __launch_bounds__(512, 2) void lstm_rec(
    const f16* __restrict__ wra, const f16* __restrict__ pre, float* __restrict__ out,
    unsigned* __restrict__ hg) {
  __shared__ f16 hl[2][16 * 264];   // [parity][16 rows][256 u + 8 pad] (528B row stride)
  const int wg = blockIdx.x;
  const int dir = wg >> 3, bblk = (wg >> 1) & 3, half = wg & 1;
  const int ph = half ^ 1;
  const int pwg = wg ^ 1;
  const int tid = threadIdx.x;
  const int lane = tid & 63, w = tid >> 6;
  const int r15 = lane & 15, lhi = lane >> 4;
  const int ulocal = w * 16 + r15;
  const int u = half * 128 + ulocal;          // global u of this lane's column
  const int b0 = bblk * 16 + lhi * 4;         // global batch base of this lane's 4 rows

  // B fragments: 4 gates x 8 k-tiles (128 regs; AGPR-resident ok on gfx950)
  f16x8 bfr[4][8];
  {
    const f16* wb0 = wra + (((size_t)(dir * 2 + half) * 8 + w) * 4) * 8 * 512;
#pragma unroll
    for (int g = 0; g < 4; ++g)
#pragma unroll
      for (int ks = 0; ks < 8; ++ks)
        bfr[g][ks] = *(const f16x8*)(wb0 + ((size_t)g * 8 + ks) * 512 + (size_t)lane * 8);
  }

  for (int i = tid; i < 2 * 16 * 264; i += 512) ((f16*)hl)[i] = (f16)0.f;
  __syncthreads();
  float cst[4] = {0.f, 0.f, 0.f, 0.f};
  const u64* pstage = (const u64*)((const char*)hg + (size_t)pwg * 8192);  // [2 par][512 u64]
  unsigned* myhg = (unsigned*)((char*)hg + (size_t)wg * 8192);             // [2 par][1024 u32]
  const int srow = tid >> 5;          // stage row (32 u64 per row)
  const int schunk = tid & 31;        // stage 8B chunk within 128-f16 half

  // pointer-increment addressing for pre/out (g offsets are 13-bit immediates)
  const unsigned short* pr16 = (const unsigned short*)pre;
  const int t0 = dir ? (TT - 1) : 0;
  const ptrdiff_t sPre = dir ? -2048 : 2048;            // u16 elems per t-step
  const ptrdiff_t sOut = dir ? -(ptrdiff_t)DD : DD;     // f32 elems per t-step
  const unsigned short* prp[4];
  float* outp[4];
#pragma unroll
  for (int j = 0; j < 4; ++j) {
    prp[j]  = pr16 + ((size_t)(b0 + j) * TT + t0) * 2048 + dir * 1024 + u;
    outp[j] = out  + ((size_t)(b0 + j) * TT + t0) * DD   + dir * 256  + u;
  }

  for (int s = 0; s < TT; ++s) {
    // pre loads (latency hides under retry)
    unsigned short pld[4][4];
#pragma unroll
    for (int g = 0; g < 4; ++g)
#pragma unroll
      for (int j = 0; j < 4; ++j)
        pld[g][j] = prp[j][g * 256];

    if (s > 0) {
      // single-RT consume: data load IS the readiness signal
      const u64* pb = pstage + (size_t)(s & 1) * 512 + tid;
      const u64 expv = 0x0001000100010001ULL * (u64)(s & 3);
      u64 v8;
      do {
        v8 = __hip_atomic_load(pb, __ATOMIC_RELAXED, __HIP_MEMORY_SCOPE_AGENT);
      } while ((v8 & 0x0003000300030003ULL) != expv);
      *(u64*)((char*)hl[s & 1] + srow * 528 + ph * 256 + schunk * 8) = v8;
    }
    __syncthreads();   // staged partner half + own-half writes (prev iter) visible

    // MFMA: full K=256 from hl[s&1]
    f32x4 accv[4] = {};
    {
      const char* hb = (const char*)hl[s & 1];
#pragma unroll
      for (int ks = 0; ks < 8; ++ks) {
        f16x8 af = *(const f16x8*)(hb + r15 * 528 + ks * 64 + lhi * 16);
#pragma unroll
        for (int g = 0; g < 4; ++g)
          accv[g] = __builtin_amdgcn_mfma_f32_16x16x32_f16(af, bfr[g][ks], accv[g], 0, 0, 0);
      }
    }

    // gates (rcp transcendentals — R11-proven)
    float hv[4];
#pragma unroll
    for (int j = 0; j < 4; ++j) {
      float zi = accv[0][j] + (float)__builtin_bit_cast(f16, pld[0][j]);
      float zf = accv[1][j] + (float)__builtin_bit_cast(f16, pld[1][j]);
      float zg = accv[2][j] + (float)__builtin_bit_cast(f16, pld[2][j]);
      float zo = accv[3][j] + (float)__builtin_bit_cast(f16, pld[3][j]);
      float ig = sigm(zi), fg = sigm(zf), gg = tanh_(zg), og = sigm(zo);
      float cc = fg * cst[j] + ig * gg;
      cst[j] = cc;
      hv[j] = og * tanh_(cc);
    }

    // publish IMMEDIATELY: tagged packed pairs, fire-and-forget (no drain, no flag)
    const unsigned tg2 = (unsigned)((s + 1) & 3);
    unsigned short t0_ = (unsigned short)((__builtin_bit_cast(unsigned short, (f16)hv[0]) & 0xFFFCu) | tg2);
    unsigned short t1_ = (unsigned short)((__builtin_bit_cast(unsigned short, (f16)hv[1]) & 0xFFFCu) | tg2);
    unsigned short t2_ = (unsigned short)((__builtin_bit_cast(unsigned short, (f16)hv[2]) & 0xFFFCu) | tg2);
    unsigned short t3_ = (unsigned short)((__builtin_bit_cast(unsigned short, (f16)hv[3]) & 0xFFFCu) | tg2);
    {
      unsigned o0 = (unsigned)__shfl_xor((int)t0_, 1, 64);
      unsigned o1 = (unsigned)__shfl_xor((int)t1_, 1, 64);
      unsigned o2 = (unsigned)__shfl_xor((int)t2_, 1, 64);
      unsigned o3 = (unsigned)__shfl_xor((int)t3_, 1, 64);
      if (!(lane & 1)) {
        unsigned* so = myhg + (size_t)((s + 1) & 1) * 1024 + (lhi * 4) * 64 + (ulocal >> 1);
        __hip_atomic_store(so,       (unsigned)t0_ | (o0 << 16), __ATOMIC_RELAXED, __HIP_MEMORY_SCOPE_AGENT);
        __hip_atomic_store(so + 64,  (unsigned)t1_ | (o1 << 16), __ATOMIC_RELAXED, __HIP_MEMORY_SCOPE_AGENT);
        __hip_atomic_store(so + 128, (unsigned)t2_ | (o2 << 16), __ATOMIC_RELAXED, __HIP_MEMORY_SCOPE_AGENT);
        __hip_atomic_store(so + 192, (unsigned)t3_ | (o3 << 16), __ATOMIC_RELAXED, __HIP_MEMORY_SCOPE_AGENT);
      }
    }

    // own h into next-parity LDS, then out stores (off the signal path)
    {
      f16* hn = hl[(s + 1) & 1];
#pragma unroll
      for (int j = 0; j < 4; ++j)
        hn[(lhi * 4 + j) * 264 + half * 128 + ulocal] = (f16)hv[j];
    }
#pragma unroll
    for (int j = 0; j < 4; ++j) {
      *outp[j] = hv[j];
      outp[j] += sOut;
      prp[j]  += sPre;
    }
  }
}

// ---------------- launch ----------------
extern "C" void kernel_launch(void* const* d_in, const int* in_sizes, int n_in,
                              void* d_out, int out_size, void* d_ws, size_t ws_size,
                              hipStream_t stream) {
  (void)in_sizes; (void)n_in; (void)out_size; (void)ws_size;
  char* ws = (char*)d_ws;
  f16* xa   = (f16*)(ws + OFF_XA);
  f16* xb   = (f16*)(ws + OFF_XB);
  f16* kwa  = (f16*)(ws + OFF_KWA);
  f16* wka  = (f16*)(ws + OFF_WKA);
  f16* wra  = (f16*)(ws + OFF_WRA);
  float* scsh = (float*)(ws + OFF_SCSH);
  f16* pre  = (f16*)(ws + OFF_PRE);
  unsigned* hg = (unsigned*)(ws + OFF_HG);

  const float* x   = (const float*)d_in[0];
  const float* ck  = (const float*)d_in[1];
  const float* cb  = (const float*)d_in[2];
  const float* gm  = (const float*)d_in[3];
  const float* bt  = (const float*)d_in[4];
  const float* mn  = (const float*)d_in[5];
  const float* vr  = (const float*)d_in[6];
  const float* wkf = (const float*)d_in[7];
  const float* wrf = (const float*)d_in[8];
  const float* bf  = (const float*)d_in[9];
  const float* wkb = (const float*)d_in[10];
  const float* wrb = (const float*)d_in[11];
  const float* bb2 = (const float*)d_in[12];

  prep_scale<<<128, 256, 0, stream>>>(cb, gm, bt, mn, vr, scsh, hg);
  prep_x<<<(BB * TP * DD) / 256, 256, 0, stream>>>(x, xa, xb);
  prep_convw<<<(3 * 5 * 512 * 512) / 256, 256, 0, stream>>>(ck, kwa);
  prep_wk<<<(512 * 2048) / 256, 256, 0, stream>>>(wkf, wkb, wka);
  prep_wr<<<(2 * 256 * 1024) / 256, 256, 0, stream>>>(wrf, wrb, wra);

  conv_gemm<<<2048, 256, 0, stream>>>(xa, xb, kwa,                  scsh,          scsh + 1536);
  conv_gemm<<<2048, 256, 0, stream>>>(xb, xa, kwa + 1 * 160 * 8192, scsh + 512,   scsh + 1536 + 512);
  conv_gemm<<<2048, 256, 0, stream>>>(xa, xb, kwa + 2 * 160 * 8192, scsh + 1024,  scsh + 1536 + 1024);

  in_gemm<<<8192, 256, 0, stream>>>(xb, pre, wka, bf, bb2);

  lstm_rec<<<16, 512, 0, stream>>>(wra, pre, (float*)d_out, hg);
}